// Round 11
// baseline (3869.454 us; speedup 1.0000x reference)
//
#include <hip/hip_runtime.h>
#include <hip/hip_fp16.h>
#include <hip/hip_fp8.h>
#include <cmath>

// ---------------------------------------------------------------------------
// LMU fused recurrence.  One 128x1536 @ 1536x1536 GEMM per step (tanh on
// first 1024 cols, linear on last 512), x-dependent rank-1 bias.
// r29 = r28 (best, 3.29 ms) + M-LO PLANE IN FP8 E4M3.
//   The last in-budget byte cut.  The m-state lo plane carries only the
//   f16 residual (needs ~4-5 extra mantissa bits, not 11): store it as
//   fp8 e4m3 (1B) instead of f16 (2B).  Fill 64 -> 56 KB/CU/step (-12.5%);
//   lo-stores halved.  fp8->f16 conversion is EXACT, so the aB MFMA path
//   is numerically identical except for the coarser lo quantization.
//   Precision: m effective 22 -> ~15 bits; per-step ~6e-5*|m|; marginally-
//   stable random walk x sqrt(784) ~ 1.7e-3 relative in m; through W_m
//   (0.036*sqrt(512)~0.8) -> est. 2-4e-3 output absmax vs 9.6e-3 threshold.
//   Range: stored = residual*2048 <= 2|m| <= 448 for |m|<224 (e4m3 max).
//   Calibration (r23: 32 KB <-> 0.58 us/step): expect -0.1..-0.15 us/step.
// Falsified-levers ledger (all counter-verified):
//   r19 2x occupancy null; r20 per-producer flags +3%; r22 dual pipeline
//   2.2x worse (RMW storm); r24 poll backoff null; r25 load staging null;
//   r26 per-wave arrive/poll 2x worse (>32 pollers = storm); r27 register
//   W_hi -4% (LDS streaming hidden).  PAID: r23 h-lo cut -12%, r28 xt
//   prefetch -0.8% -- bytes on the serial path are the only lever.
//   Locked-in: barrier words touched by atomic RMWs ONLY (r16/r12/r14);
//   tid0-ONLY polling (r26).
// Pre-commitment: absmax fail OR dur >= 3270 -> ROOFLINE, final = r28.
// Design = r28:
//   - h state f16 HI-ONLY; m hi f16 + lo fp8.  Interleaved kt sets
//     (wave w owns kt = w+4*ki; ki>=8 <=> m-cols, 4 lo-kts per wave).
//   - XCD-local islands (s_getreg XCC_ID + rank registration, 1 WG/CU).
//   - Flat per-island arrival counter in LOCAL XCD L2; tid0 arrival RMW,
//     tid0 poll = asm global_atomic_add +0 sc0 with s_sleep(4) backoff.
//   - W_lo register-resident (144 AGPRs); W_hi slice (147 KB) in LDS.
//   - Phase-1 staged state loads + xt float4 prefetch; per-step buffer_inv.
// ---------------------------------------------------------------------------

typedef _Float16 half8 __attribute__((ext_vector_type(8)));
typedef float floatx4 __attribute__((ext_vector_type(4)));
typedef unsigned char uchar8 __attribute__((ext_vector_type(8)));

#define NSTATE   1536
#define BATCH    128
#define TSTEPS   784
#define KTILES   48
#define ISL_WGS  32                  // WGs per island (= CUs per XCD)
#define SLICE_H8 9216                // half8 per 48-col weight slice (48*3*64)
#define LO_SCALE 2048.0f
#define LO_INV   (1.0f / 2048.0f)
#define MCOLS    512

__device__ __align__(16) _Float16 g_Whi[NSTATE * NSTATE];
__device__ __align__(16) _Float16 g_Wlo[NSTATE * NSTATE];
__device__ float    g_wb[NSTATE];
__device__ float    g_WmA[1024 * 512];
__device__ float    g_WmB[1024];
__device__ __align__(16) _Float16 g_Shi[2 * BATCH * NSTATE];
__device__ __align__(8)  unsigned char g_Slo8[2 * BATCH * MCOLS];  // m-lo, fp8
// [xcd*64]: island arrival counters; [512 + xcd*64]: registration counters
__device__ unsigned g_bar[1024];

// Forced local-L2 atomic RMW poll (returns pre-add value).  InstCombine
// cannot demote this to a (stale-L1-cacheable) load -- r12/r14 lessons.
__device__ __forceinline__ unsigned poll_rmw(unsigned* p) {
    unsigned old;
    asm volatile("global_atomic_add %0, %1, %2, off sc0\n\ts_waitcnt vmcnt(0)"
                 : "=&v"(old)
                 : "v"(p), "v"(0u)
                 : "memory");
    return old;
}

// Branch-free tanh: 1 - 2/(e^{2x}+1).  __expf -> v_exp_f32.  Exact limits:
// e=inf -> 1, e=0 -> -1.  |err| ~1e-7.
__device__ __forceinline__ float fast_tanh(float x) {
    float e = __expf(2.f * x);
    return 1.f - 2.f / (e + 1.f);
}

// W_mB[i] = sum_c W_m[i,c] * BT[c]
__global__ void prep_wmb(const float* __restrict__ Wm, const float* __restrict__ BT) {
    int row  = blockIdx.x * 4 + (threadIdx.x >> 6);
    int lane = threadIdx.x & 63;
    float s = 0.f;
    for (int c = lane; c < 512; c += 64) s += Wm[row * 512 + c] * BT[c];
    for (int o = 32; o; o >>= 1) s += __shfl_down(s, o);
    if (lane == 0) g_WmB[row] = s;
}

// W_mA = W_m @ (I + AT)
__global__ void prep_wma(const float* __restrict__ Wm, const float* __restrict__ AT) {
    __shared__ float As[32][33], Bs[32][33];
    int d0 = blockIdx.x * 32, i0 = blockIdx.y * 32;
    int tx = threadIdx.x & 31, ty = threadIdx.x >> 5;
    float acc[4];
#pragma unroll
    for (int r = 0; r < 4; ++r) acc[r] = Wm[(i0 + ty + 8 * r) * 512 + d0 + tx];
    for (int c0 = 0; c0 < 512; c0 += 32) {
#pragma unroll
        for (int r = 0; r < 4; ++r) {
            As[ty + 8 * r][tx] = Wm[(i0 + ty + 8 * r) * 512 + c0 + tx];
            Bs[ty + 8 * r][tx] = AT[(c0 + ty + 8 * r) * 512 + d0 + tx];
        }
        __syncthreads();
#pragma unroll
        for (int c = 0; c < 32; ++c)
#pragma unroll
            for (int r = 0; r < 4; ++r) acc[r] += As[ty + 8 * r][c] * Bs[c][tx];
        __syncthreads();
    }
#pragma unroll
    for (int r = 0; r < 4; ++r) g_WmA[(i0 + ty + 8 * r) * 512 + d0 + tx] = acc[r];
}

// Build W_full, f16 hi/lo (lo x2048), in slice-major fragment order:
// storage s = (((sl*48 + kt)*3 + nt)*64 + lane)*8 + j
//   n = sl*48 + nt*16 + (lane&15),  k = kt*32 + ((lane>>4)&3)*8 + j
__global__ void prep_wfull(const float* __restrict__ Wh, const float* __restrict__ AT,
                           const float* __restrict__ BT, const float* __restrict__ eh,
                           const float* __restrict__ em, const float* __restrict__ ex,
                           const float* __restrict__ Wx) {
    int s = blockIdx.x * 256 + threadIdx.x;     // [0, 1536*1536)
    int j8 = s & 7;
    int u = s >> 3;
    int lane = u & 63;
    u >>= 6;                                    // [0, 4608)
    int nt = u % 3; u /= 3;
    int kt = u % 48;
    int sl = u / 48;
    int n = sl * 48 + nt * 16 + (lane & 15);
    int k = kt * 32 + ((lane >> 4) & 3) * 8 + j8;

    float w;
    if (n < 1024) {
        if (k < 1024) w = Wh[n * 1024 + k] + g_WmB[n] * eh[k];
        else          w = g_WmA[n * 512 + (k - 1024)] + g_WmB[n] * em[k - 1024];
    } else {
        int c = n - 1024;
        if (k < 1024) w = BT[c] * eh[k];
        else {
            int d = k - 1024;
            w = ((c == d) ? 1.f : 0.f) + AT[c * 512 + d] + BT[c] * em[d];
        }
    }
    _Float16 hi = (_Float16)w;
    g_Whi[s] = hi;
    g_Wlo[s] = (_Float16)((w - (float)hi) * LO_SCALE);

    if (s < NSTATE) {
        float b = (s < 1024) ? (Wx[s] + ex[0] * g_WmB[s]) : (BT[s - 1024] * ex[0]);
        g_wb[s] = b;
    }
    if (s < 2 * BATCH * NSTATE) g_Shi[s] = (_Float16)0.f;
    if (s < 2 * BATCH * MCOLS) g_Slo8[s] = 0;   // fp8 zero = 0x00
    if (s < 1024) g_bar[s] = 0u;
}

__launch_bounds__(256, 1)
__global__ void lmu_persist(const float* __restrict__ inputs) {
    __shared__ half8  lwh[SLICE_H8];            // 147456 B: W_hi slice
    __shared__ float4 red[4 * 3 * 64];          // 12288 B: K-split partials
    __shared__ int    s_sl;

    const int tid = threadIdx.x;

    // ---- physical XCD id + rank registration (island = XCD) ----
    unsigned xcd;
    asm volatile("s_getreg_b32 %0, hwreg(HW_REG_XCC_ID)" : "=s"(xcd));
    xcd &= 7u;
    if (tid == 0) {
        unsigned rank = __hip_atomic_fetch_add(g_bar + 512 + xcd * 64, 1u,
                                               __ATOMIC_RELAXED,
                                               __HIP_MEMORY_SCOPE_WORKGROUP);
        s_sl = (int)(rank & 31u);               // column slice [0,32)
    }
    __syncthreads();
    const int isl = (int)xcd;                   // batch rows isl*16..+16
    const int sl  = s_sl;                       // cols sl*48..+48

    // stage W_hi slice -> LDS
    {
        const half8* src = (const half8*)g_Whi + (size_t)sl * SLICE_H8;
        for (int i = tid; i < SLICE_H8; i += 256) lwh[i] = src[i];
    }

    const int lane = tid & 63, wv = tid >> 6;
    const int quad = lane >> 4, l16 = lane & 15;
    const int rowA = isl * 16 + l16;            // A-frag batch row
    unsigned* cnt = g_bar + isl * 64;           // island arrival counter (local L2)

    // INTERLEAVED kt set: wave wv owns kt = wv + 4*ki, ki in [0,12).
    // ki>=8 <=> kt>=32 <=> m-columns (lo plane live) -- 4 per wave, balanced.

    // epilogue constants (wave wv<3 handles nt=wv)
    const int ncol = sl * 48 + wv * 16 + l16;
    const float wbv = (wv < 3) ? g_wb[ncol] : 0.f;
    const bool do_tanh = (sl * 48 + wv * 16) < 1024;   // h-granule: no lo store

    // ---- W_lo: FULLY register-resident (36 x half8 = 144 AGPRs), loaded once
    half8 wr[12 * 3];
    {
        const half8* wlo = (const half8*)g_Wlo + (size_t)sl * SLICE_H8;
#pragma unroll
        for (int ki = 0; ki < 12; ++ki)
#pragma unroll
            for (int nt = 0; nt < 3; ++nt)
                wr[ki * 3 + nt] = wlo[((wv + 4 * ki) * 3 + nt) * 64 + lane];
    }

    __syncthreads();

    int buf = 0;
    for (int t = 0; t < TSTEPS; ++t) {
        // PLAIN loads: producers share this XCD's L2 -> L2-local traffic
        const _Float16* shr =
            g_Shi + buf * BATCH * NSTATE + rowA * NSTATE + quad * 8;
        const unsigned char* sl8r =
            g_Slo8 + buf * BATCH * MCOLS + rowA * MCOLS + quad * 8;

        // ---- PHASE 1: issue ALL state loads into registers (r25/r28):
        // 12 hi half8, 4 lo fp8x8 (8B), and this step's x-column float4.
        float4 xt4 = *(const float4*)(inputs + t * BATCH + isl * 16 + quad * 4);
        half8 sa[12];
        uchar8 sb8[4];
#pragma unroll
        for (int ki = 0; ki < 8; ++ki)
            sa[ki] = *(const half8*)(shr + (wv + 4 * ki) * 32);
#pragma unroll
        for (int ki = 8; ki < 12; ++ki) {
            sa[ki]     = *(const half8*)(shr + (wv + 4 * ki) * 32);
            sb8[ki - 8] = *(const uchar8*)(sl8r + (wv + 4 * ki - 32) * 32);
        }
        __builtin_amdgcn_sched_barrier(0);

        // fp8 -> f16 (exact): sb feeds the same f16 MFMA path as before.
        half8 sb[4];
#pragma unroll
        for (int q8 = 0; q8 < 4; ++q8)
#pragma unroll
            for (int j = 0; j < 8; ++j) {
                __hip_fp8_e4m3 f8;
                f8.__x = sb8[q8][j];
                sb[q8][j] = (_Float16)(float)f8;
            }

        // ---- PHASE 2: MFMA over the staged registers + LDS W_hi ----
        floatx4 aA[3], aB[3], aC[3];
#pragma unroll
        for (int q = 0; q < 3; ++q) { aA[q] = (floatx4)0.f; aB[q] = (floatx4)0.f; aC[q] = (floatx4)0.f; }

#pragma unroll
        for (int ki = 0; ki < 12; ++ki) {
            const int kt = wv + 4 * ki;
#pragma unroll
            for (int nt = 0; nt < 3; ++nt) {
                half8 bh = lwh[(kt * 3 + nt) * 64 + lane];
                aA[nt] = __builtin_amdgcn_mfma_f32_16x16x32_f16(sa[ki], bh, aA[nt], 0, 0, 0);
                if (ki >= 8)
                    aB[nt] = __builtin_amdgcn_mfma_f32_16x16x32_f16(sb[ki - 8], bh, aB[nt], 0, 0, 0);
                aC[nt] = __builtin_amdgcn_mfma_f32_16x16x32_f16(sa[ki], wr[ki * 3 + nt], aC[nt], 0, 0, 0);
            }
        }

        // K-split partials -> LDS
#pragma unroll
        for (int nt = 0; nt < 3; ++nt) {
            floatx4 P = aA[nt] + (aB[nt] + aC[nt]) * LO_INV;
            red[(wv * 3 + nt) * 64 + lane] = float4{P[0], P[1], P[2], P[3]};
        }
        __syncthreads();

        // waves 0-2: reduce + bias + activation + hi/lo split + PLAIN store
        const int nbuf = buf ^ 1;
        if (wv < 3) {
            float4 v0 = red[(0 * 3 + wv) * 64 + lane];
            float4 v1 = red[(1 * 3 + wv) * 64 + lane];
            float4 v2 = red[(2 * 3 + wv) * 64 + lane];
            float4 v3 = red[(3 * 3 + wv) * 64 + lane];
            float vr4[4] = {v0.x + v1.x + v2.x + v3.x, v0.y + v1.y + v2.y + v3.y,
                            v0.z + v1.z + v2.z + v3.z, v0.w + v1.w + v2.w + v3.w};
            const float vx[4] = {xt4.x, xt4.y, xt4.z, xt4.w};
            _Float16* dh = g_Shi + nbuf * BATCH * NSTATE;
            unsigned char* dl8 = g_Slo8 + nbuf * BATCH * MCOLS;
            if (do_tanh) {
                // h-granule: f16 hi only, no lo store
#pragma unroll
                for (int r = 0; r < 4; ++r) {
                    int b = isl * 16 + quad * 4 + r;
                    float v = fast_tanh(vr4[r] + vx[r] * wbv);
                    dh[b * NSTATE + ncol] = (_Float16)v;
                }
            } else {
                // m-granule: f16 hi + fp8 lo (residual x2048, e4m3-sat)
                const int mcol = ncol - 1024;
#pragma unroll
                for (int r = 0; r < 4; ++r) {
                    int b = isl * 16 + quad * 4 + r;
                    float v = vr4[r] + vx[r] * wbv;
                    _Float16 hi = (_Float16)v;
                    dh[b * NSTATE + ncol] = hi;
                    __hip_fp8_e4m3 lo8((v - (float)hi) * LO_SCALE);
                    dl8[b * MCOLS + mcol] = lo8.__x;
                }
            }
        }

        // drain stores (syncthreads emits vmcnt(0)), then flat LOCAL-L2
        // barrier: arrival = wg-scope RMW(+1); poll = tid0-ONLY asm RMW(+0)
        // sc0 with s_sleep(4) backoff (r26: >32 pollers = RMW storm).
        __builtin_amdgcn_fence(__ATOMIC_RELEASE, "workgroup");
        __syncthreads();
        if (tid == 0) {
            __hip_atomic_fetch_add(cnt, 1u, __ATOMIC_RELAXED,
                                   __HIP_MEMORY_SCOPE_WORKGROUP);
            const unsigned target = (unsigned)ISL_WGS * (unsigned)(t + 1);
            int spin = 0;
            while (poll_rmw(cnt) < target) {
                __builtin_amdgcn_s_sleep(4);    // ~256 cy low-power backoff
                if (++spin > (1 << 18)) break;  // deadman: no hang
            }
        }
        __syncthreads();
        // CU-local L1 invalidate only (L2 holds the island's fresh state)
        asm volatile("buffer_inv\n\ts_waitcnt vmcnt(0)" ::: "memory");
        __builtin_amdgcn_fence(__ATOMIC_ACQUIRE, "workgroup");
        buf = nbuf;
    }
}

// logits + softmax: one WG per batch row (final state in plane 0: 784 even;
// dispatch boundary flushes every XCD's L2 so state is globally visible).
// h is f16 HI-ONLY (cols < 1024 feed the dense layer).
__global__ void lmu_out(const float* __restrict__ Wd, const float* __restrict__ bd,
                        float* __restrict__ out) {
    __shared__ float red[272];
    int b = blockIdx.x;
    const _Float16* sh = g_Shi + b * NSTATE;
    int tid = threadIdx.x;
    int c = tid & 15, chunk = tid >> 4;
    float part = 0.f;
    if (c < 10) {
        for (int i = chunk * 64; i < chunk * 64 + 64; ++i)
            part += (float)sh[i] * Wd[c * 1024 + i];
    }
    red[chunk * 16 + c] = part;
    __syncthreads();
    if (tid < 10) {
        float lg = bd[tid];
        for (int q = 0; q < 16; ++q) lg += red[q * 16 + tid];
        red[256 + tid] = lg;
    }
    __syncthreads();
    if (tid < 10) {
        float mx = red[256];
        for (int q = 1; q < 10; ++q) mx = fmaxf(mx, red[256 + q]);
        float sm = 0.f;
        for (int q = 0; q < 10; ++q) sm += expf(red[256 + q] - mx);
        out[b * 10 + tid] = expf(red[256 + tid] - mx) / sm;
    }
}

extern "C" void kernel_launch(void* const* d_in, const int* in_sizes, int n_in,
                              void* d_out, int out_size, void* d_ws, size_t ws_size,
                              hipStream_t stream) {
    const float* inputs = (const float*)d_in[0];
    const float* e_x    = (const float*)d_in[1];
    const float* e_h    = (const float*)d_in[2];
    const float* e_m    = (const float*)d_in[3];
    const float* W_x    = (const float*)d_in[4];
    const float* W_h    = (const float*)d_in[5];
    const float* W_m    = (const float*)d_in[6];
    const float* AT     = (const float*)d_in[7];
    const float* BT     = (const float*)d_in[8];
    const float* W_d    = (const float*)d_in[9];
    const float* b_d    = (const float*)d_in[10];
    (void)d_ws; (void)ws_size; (void)in_sizes; (void)n_in;

    prep_wmb<<<256, 256, 0, stream>>>(W_m, BT);
    prep_wma<<<dim3(16, 32), 256, 0, stream>>>(W_m, AT);
    prep_wfull<<<9216, 256, 0, stream>>>(W_h, AT, BT, e_h, e_m, e_x, W_x);

    lmu_persist<<<256, 256, 0, stream>>>(inputs);

    lmu_out<<<128, 256, 0, stream>>>(W_d, b_d, (float*)d_out);
}

// Round 12
// 3274.415 us; speedup vs baseline: 1.1817x; 1.1817x over previous
//
#include <hip/hip_runtime.h>
#include <hip/hip_fp16.h>
#include <cmath>

// ---------------------------------------------------------------------------
// LMU fused recurrence.  One 128x1536 @ 1536x1536 GEMM per step (tanh on
// first 1024 cols, linear on last 512), x-dependent rank-1 bias.
// r30 = r28 VERBATIM (best, 3.29 ms).  r29 (m-lo in fp8) REVERTED: the
// fp8->f16 decode put ~100+ scalar VALU ops on the serial pre-MFMA path
// (VALUBusy 8.6->10.2, MfmaUtil 13.6->11.5, dur 3292->3869) -- decode cost
// exceeded the 8 KB/CU fill saving.  Byte-cut lever exhausted.
// FINAL KERNEL.  Structural floor (counter-backed ledger):
//   ~1.0 us/step L2-local state fill (service-bound: r19 occupancy null,
//     r25 load staging null, r27 register-resident weights null/-4%),
//   ~0.9 us island-barrier round-trips (r15 tree, r17 sweep, r20 flags,
//     r24 backoff, r26 per-wave poll: all null or worse),
//   ~0.7 us MFMA + LDS reduce + epilogue,
//   at DVFS-depressed clock.  PAID levers: r23 h-lo cut (-12%), r28 xt
//   prefetch (-0.8%).  Session: 3909 -> 3292 us (-16%).
//   Locked-in: barrier words touched by atomic RMWs ONLY (r16 races; r12
//   InstCombine demotes fetch_add(0) to a load; r14 sc0 loads served stale
//   from L1); tid0-ONLY polling (r26: >32 pollers = RMW storm).
// Design:
//   - h state f16 HI-ONLY; m keeps hi/lo (lo x2048).  Interleaved kt sets
//     (wave w owns kt = w+4*ki; ki>=8 <=> m-cols, 4 lo-kts per wave).
//   - XCD-local islands (s_getreg XCC_ID + rank registration, 1 WG/CU).
//   - Flat per-island arrival counter in LOCAL XCD L2; tid0 arrival RMW,
//     tid0 poll = asm global_atomic_add +0 sc0 with s_sleep(4) backoff.
//   - W_lo register-resident (144 AGPRs); W_hi slice (147 KB) in LDS.
//   - Phase-1 staged state loads + xt float4 prefetch; per-step buffer_inv.
// Precision: f16 hi/lo weights (lo x2048), m-state hi/lo, h-state hi-only,
// fp32 MFMA accumulate.  Verified absmax 9.8e-4 (threshold 9.6e-3).
// ---------------------------------------------------------------------------

typedef _Float16 half8 __attribute__((ext_vector_type(8)));
typedef float floatx4 __attribute__((ext_vector_type(4)));

#define NSTATE   1536
#define BATCH    128
#define TSTEPS   784
#define KTILES   48
#define ISL_WGS  32                  // WGs per island (= CUs per XCD)
#define SLICE_H8 9216                // half8 per 48-col weight slice (48*3*64)
#define LO_SCALE 2048.0f
#define LO_INV   (1.0f / 2048.0f)

__device__ __align__(16) _Float16 g_Whi[NSTATE * NSTATE];
__device__ __align__(16) _Float16 g_Wlo[NSTATE * NSTATE];
__device__ float    g_wb[NSTATE];
__device__ float    g_WmA[1024 * 512];
__device__ float    g_WmB[1024];
__device__ __align__(16) _Float16 g_Shi[2 * BATCH * NSTATE];
__device__ __align__(16) _Float16 g_Slo[2 * BATCH * NSTATE];
// [xcd*64]: island arrival counters; [512 + xcd*64]: registration counters
__device__ unsigned g_bar[1024];

// Forced local-L2 atomic RMW poll (returns pre-add value).  InstCombine
// cannot demote this to a (stale-L1-cacheable) load -- r12/r14 lessons.
__device__ __forceinline__ unsigned poll_rmw(unsigned* p) {
    unsigned old;
    asm volatile("global_atomic_add %0, %1, %2, off sc0\n\ts_waitcnt vmcnt(0)"
                 : "=&v"(old)
                 : "v"(p), "v"(0u)
                 : "memory");
    return old;
}

// Branch-free tanh: 1 - 2/(e^{2x}+1).  __expf -> v_exp_f32.  Exact limits:
// e=inf -> 1, e=0 -> -1.  |err| ~1e-7.
__device__ __forceinline__ float fast_tanh(float x) {
    float e = __expf(2.f * x);
    return 1.f - 2.f / (e + 1.f);
}

// W_mB[i] = sum_c W_m[i,c] * BT[c]
__global__ void prep_wmb(const float* __restrict__ Wm, const float* __restrict__ BT) {
    int row  = blockIdx.x * 4 + (threadIdx.x >> 6);
    int lane = threadIdx.x & 63;
    float s = 0.f;
    for (int c = lane; c < 512; c += 64) s += Wm[row * 512 + c] * BT[c];
    for (int o = 32; o; o >>= 1) s += __shfl_down(s, o);
    if (lane == 0) g_WmB[row] = s;
}

// W_mA = W_m @ (I + AT)
__global__ void prep_wma(const float* __restrict__ Wm, const float* __restrict__ AT) {
    __shared__ float As[32][33], Bs[32][33];
    int d0 = blockIdx.x * 32, i0 = blockIdx.y * 32;
    int tx = threadIdx.x & 31, ty = threadIdx.x >> 5;
    float acc[4];
#pragma unroll
    for (int r = 0; r < 4; ++r) acc[r] = Wm[(i0 + ty + 8 * r) * 512 + d0 + tx];
    for (int c0 = 0; c0 < 512; c0 += 32) {
#pragma unroll
        for (int r = 0; r < 4; ++r) {
            As[ty + 8 * r][tx] = Wm[(i0 + ty + 8 * r) * 512 + c0 + tx];
            Bs[ty + 8 * r][tx] = AT[(c0 + ty + 8 * r) * 512 + d0 + tx];
        }
        __syncthreads();
#pragma unroll
        for (int c = 0; c < 32; ++c)
#pragma unroll
            for (int r = 0; r < 4; ++r) acc[r] += As[ty + 8 * r][c] * Bs[c][tx];
        __syncthreads();
    }
#pragma unroll
    for (int r = 0; r < 4; ++r) g_WmA[(i0 + ty + 8 * r) * 512 + d0 + tx] = acc[r];
}

// Build W_full, f16 hi/lo (lo x2048), in slice-major fragment order:
// storage s = (((sl*48 + kt)*3 + nt)*64 + lane)*8 + j
//   n = sl*48 + nt*16 + (lane&15),  k = kt*32 + ((lane>>4)&3)*8 + j
__global__ void prep_wfull(const float* __restrict__ Wh, const float* __restrict__ AT,
                           const float* __restrict__ BT, const float* __restrict__ eh,
                           const float* __restrict__ em, const float* __restrict__ ex,
                           const float* __restrict__ Wx) {
    int s = blockIdx.x * 256 + threadIdx.x;     // [0, 1536*1536)
    int j8 = s & 7;
    int u = s >> 3;
    int lane = u & 63;
    u >>= 6;                                    // [0, 4608)
    int nt = u % 3; u /= 3;
    int kt = u % 48;
    int sl = u / 48;
    int n = sl * 48 + nt * 16 + (lane & 15);
    int k = kt * 32 + ((lane >> 4) & 3) * 8 + j8;

    float w;
    if (n < 1024) {
        if (k < 1024) w = Wh[n * 1024 + k] + g_WmB[n] * eh[k];
        else          w = g_WmA[n * 512 + (k - 1024)] + g_WmB[n] * em[k - 1024];
    } else {
        int c = n - 1024;
        if (k < 1024) w = BT[c] * eh[k];
        else {
            int d = k - 1024;
            w = ((c == d) ? 1.f : 0.f) + AT[c * 512 + d] + BT[c] * em[d];
        }
    }
    _Float16 hi = (_Float16)w;
    g_Whi[s] = hi;
    g_Wlo[s] = (_Float16)((w - (float)hi) * LO_SCALE);

    if (s < NSTATE) {
        float b = (s < 1024) ? (Wx[s] + ex[0] * g_WmB[s]) : (BT[s - 1024] * ex[0]);
        g_wb[s] = b;
    }
    if (s < 2 * BATCH * NSTATE) { g_Shi[s] = (_Float16)0.f; g_Slo[s] = (_Float16)0.f; }
    if (s < 1024) g_bar[s] = 0u;
}

__launch_bounds__(256, 1)
__global__ void lmu_persist(const float* __restrict__ inputs) {
    __shared__ half8  lwh[SLICE_H8];            // 147456 B: W_hi slice
    __shared__ float4 red[4 * 3 * 64];          // 12288 B: K-split partials
    __shared__ int    s_sl;

    const int tid = threadIdx.x;

    // ---- physical XCD id + rank registration (island = XCD) ----
    unsigned xcd;
    asm volatile("s_getreg_b32 %0, hwreg(HW_REG_XCC_ID)" : "=s"(xcd));
    xcd &= 7u;
    if (tid == 0) {
        unsigned rank = __hip_atomic_fetch_add(g_bar + 512 + xcd * 64, 1u,
                                               __ATOMIC_RELAXED,
                                               __HIP_MEMORY_SCOPE_WORKGROUP);
        s_sl = (int)(rank & 31u);               // column slice [0,32)
    }
    __syncthreads();
    const int isl = (int)xcd;                   // batch rows isl*16..+16
    const int sl  = s_sl;                       // cols sl*48..+48

    // stage W_hi slice -> LDS
    {
        const half8* src = (const half8*)g_Whi + (size_t)sl * SLICE_H8;
        for (int i = tid; i < SLICE_H8; i += 256) lwh[i] = src[i];
    }

    const int lane = tid & 63, wv = tid >> 6;
    const int quad = lane >> 4, l16 = lane & 15;
    const int rowA = isl * 16 + l16;            // A-frag batch row
    unsigned* cnt = g_bar + isl * 64;           // island arrival counter (local L2)

    // INTERLEAVED kt set: wave wv owns kt = wv + 4*ki, ki in [0,12).
    // ki>=8 <=> kt>=32 <=> m-columns (lo plane live) -- 4 per wave, balanced.

    // epilogue constants (wave wv<3 handles nt=wv)
    const int ncol = sl * 48 + wv * 16 + l16;
    const float wbv = (wv < 3) ? g_wb[ncol] : 0.f;
    const bool do_tanh = (sl * 48 + wv * 16) < 1024;   // h-granule: no lo store

    // ---- W_lo: FULLY register-resident (36 x half8 = 144 AGPRs), loaded once
    half8 wr[12 * 3];
    {
        const half8* wlo = (const half8*)g_Wlo + (size_t)sl * SLICE_H8;
#pragma unroll
        for (int ki = 0; ki < 12; ++ki)
#pragma unroll
            for (int nt = 0; nt < 3; ++nt)
                wr[ki * 3 + nt] = wlo[((wv + 4 * ki) * 3 + nt) * 64 + lane];
    }

    __syncthreads();

    int buf = 0;
    for (int t = 0; t < TSTEPS; ++t) {
        // PLAIN loads: producers share this XCD's L2 -> L2-local traffic
        const _Float16* shr =
            g_Shi + buf * BATCH * NSTATE + rowA * NSTATE + quad * 8;
        const _Float16* slr =
            g_Slo + buf * BATCH * NSTATE + rowA * NSTATE + quad * 8;

        // ---- PHASE 1: issue ALL state loads into registers (r25), plus
        // the r28 lever: prefetch this step's x-column as ONE float4.
        // buffer_inv wiped the inputs lines from L1 last step, so the
        // epilogue's xt read was a serial post-barrier L2 round-trip;
        // issuing it here hides it under the MFMA phase (read-only data,
        // no hazard).  Lanes of quad q hold rows isl*16+q*4..+4 -- exactly
        // what their epilogue needs.
        float4 xt4 = *(const float4*)(inputs + t * BATCH + isl * 16 + quad * 4);
        half8 sa[12];
        half8 sb[4];
#pragma unroll
        for (int ki = 0; ki < 8; ++ki)
            sa[ki] = *(const half8*)(shr + (wv + 4 * ki) * 32);
#pragma unroll
        for (int ki = 8; ki < 12; ++ki) {
            sa[ki]     = *(const half8*)(shr + (wv + 4 * ki) * 32);
            sb[ki - 8] = *(const half8*)(slr + (wv + 4 * ki) * 32);
        }
        __builtin_amdgcn_sched_barrier(0);

        // ---- PHASE 2: MFMA over the staged registers + LDS W_hi ----
        floatx4 aA[3], aB[3], aC[3];
#pragma unroll
        for (int q = 0; q < 3; ++q) { aA[q] = (floatx4)0.f; aB[q] = (floatx4)0.f; aC[q] = (floatx4)0.f; }

#pragma unroll
        for (int ki = 0; ki < 12; ++ki) {
            const int kt = wv + 4 * ki;
#pragma unroll
            for (int nt = 0; nt < 3; ++nt) {
                half8 bh = lwh[(kt * 3 + nt) * 64 + lane];
                aA[nt] = __builtin_amdgcn_mfma_f32_16x16x32_f16(sa[ki], bh, aA[nt], 0, 0, 0);
                if (ki >= 8)
                    aB[nt] = __builtin_amdgcn_mfma_f32_16x16x32_f16(sb[ki - 8], bh, aB[nt], 0, 0, 0);
                aC[nt] = __builtin_amdgcn_mfma_f32_16x16x32_f16(sa[ki], wr[ki * 3 + nt], aC[nt], 0, 0, 0);
            }
        }

        // K-split partials -> LDS
#pragma unroll
        for (int nt = 0; nt < 3; ++nt) {
            floatx4 P = aA[nt] + (aB[nt] + aC[nt]) * LO_INV;
            red[(wv * 3 + nt) * 64 + lane] = float4{P[0], P[1], P[2], P[3]};
        }
        __syncthreads();

        // waves 0-2: reduce + bias + activation + hi/lo split + PLAIN store
        const int nbuf = buf ^ 1;
        if (wv < 3) {
            float4 v0 = red[(0 * 3 + wv) * 64 + lane];
            float4 v1 = red[(1 * 3 + wv) * 64 + lane];
            float4 v2 = red[(2 * 3 + wv) * 64 + lane];
            float4 v3 = red[(3 * 3 + wv) * 64 + lane];
            float vr4[4] = {v0.x + v1.x + v2.x + v3.x, v0.y + v1.y + v2.y + v3.y,
                            v0.z + v1.z + v2.z + v3.z, v0.w + v1.w + v2.w + v3.w};
            const float vx[4] = {xt4.x, xt4.y, xt4.z, xt4.w};
            _Float16* dh = g_Shi + nbuf * BATCH * NSTATE;
            _Float16* dl = g_Slo + nbuf * BATCH * NSTATE;
            if (do_tanh) {
                // h-granule: f16 hi only, no lo store
#pragma unroll
                for (int r = 0; r < 4; ++r) {
                    int b = isl * 16 + quad * 4 + r;
                    float v = fast_tanh(vr4[r] + vx[r] * wbv);
                    dh[b * NSTATE + ncol] = (_Float16)v;
                }
            } else {
                // m-granule: keep hi/lo pair
#pragma unroll
                for (int r = 0; r < 4; ++r) {
                    int b = isl * 16 + quad * 4 + r;
                    float v = vr4[r] + vx[r] * wbv;
                    _Float16 hi = (_Float16)v;
                    dh[b * NSTATE + ncol] = hi;
                    dl[b * NSTATE + ncol] = (_Float16)((v - (float)hi) * LO_SCALE);
                }
            }
        }

        // drain stores (syncthreads emits vmcnt(0)), then flat LOCAL-L2
        // barrier: arrival = wg-scope RMW(+1); poll = tid0-ONLY asm RMW(+0)
        // sc0 with s_sleep(4) backoff (r26: >32 pollers = RMW storm).
        __builtin_amdgcn_fence(__ATOMIC_RELEASE, "workgroup");
        __syncthreads();
        if (tid == 0) {
            __hip_atomic_fetch_add(cnt, 1u, __ATOMIC_RELAXED,
                                   __HIP_MEMORY_SCOPE_WORKGROUP);
            const unsigned target = (unsigned)ISL_WGS * (unsigned)(t + 1);
            int spin = 0;
            while (poll_rmw(cnt) < target) {
                __builtin_amdgcn_s_sleep(4);    // ~256 cy low-power backoff
                if (++spin > (1 << 18)) break;  // deadman: no hang
            }
        }
        __syncthreads();
        // CU-local L1 invalidate only (L2 holds the island's fresh state)
        asm volatile("buffer_inv\n\ts_waitcnt vmcnt(0)" ::: "memory");
        __builtin_amdgcn_fence(__ATOMIC_ACQUIRE, "workgroup");
        buf = nbuf;
    }
}

// logits + softmax: one WG per batch row (final state in plane 0: 784 even;
// dispatch boundary flushes every XCD's L2 so state is globally visible).
// h is f16 HI-ONLY (cols < 1024 feed the dense layer).
__global__ void lmu_out(const float* __restrict__ Wd, const float* __restrict__ bd,
                        float* __restrict__ out) {
    __shared__ float red[272];
    int b = blockIdx.x;
    const _Float16* sh = g_Shi + b * NSTATE;
    int tid = threadIdx.x;
    int c = tid & 15, chunk = tid >> 4;
    float part = 0.f;
    if (c < 10) {
        for (int i = chunk * 64; i < chunk * 64 + 64; ++i)
            part += (float)sh[i] * Wd[c * 1024 + i];
    }
    red[chunk * 16 + c] = part;
    __syncthreads();
    if (tid < 10) {
        float lg = bd[tid];
        for (int q = 0; q < 16; ++q) lg += red[q * 16 + tid];
        red[256 + tid] = lg;
    }
    __syncthreads();
    if (tid < 10) {
        float mx = red[256];
        for (int q = 1; q < 10; ++q) mx = fmaxf(mx, red[256 + q]);
        float sm = 0.f;
        for (int q = 0; q < 10; ++q) sm += expf(red[256 + q] - mx);
        out[b * 10 + tid] = expf(red[256 + tid] - mx) / sm;
    }
}

extern "C" void kernel_launch(void* const* d_in, const int* in_sizes, int n_in,
                              void* d_out, int out_size, void* d_ws, size_t ws_size,
                              hipStream_t stream) {
    const float* inputs = (const float*)d_in[0];
    const float* e_x    = (const float*)d_in[1];
    const float* e_h    = (const float*)d_in[2];
    const float* e_m    = (const float*)d_in[3];
    const float* W_x    = (const float*)d_in[4];
    const float* W_h    = (const float*)d_in[5];
    const float* W_m    = (const float*)d_in[6];
    const float* AT     = (const float*)d_in[7];
    const float* BT     = (const float*)d_in[8];
    const float* W_d    = (const float*)d_in[9];
    const float* b_d    = (const float*)d_in[10];
    (void)d_ws; (void)ws_size; (void)in_sizes; (void)n_in;

    prep_wmb<<<256, 256, 0, stream>>>(W_m, BT);
    prep_wma<<<dim3(16, 32), 256, 0, stream>>>(W_m, AT);
    prep_wfull<<<9216, 256, 0, stream>>>(W_h, AT, BT, e_h, e_m, e_x, W_x);

    lmu_persist<<<256, 256, 0, stream>>>(inputs);

    lmu_out<<<128, 256, 0, stream>>>(W_d, b_d, (float*)d_out);
}